// Round 2
// baseline (245.163 us; speedup 1.0000x reference)
//
#include <hip/hip_runtime.h>
#include <hip/hip_bf16.h>

constexpr int Bb  = 4;
constexpr int Nn  = 1024;
constexpr int Fin = 256;
constexpr int Cc  = 256;   // H*HID
constexpr int Hh  = 8;
constexpr int Hid = 32;
constexpr float Alpha = 0.2f;
constexpr float L2E = 1.4426950408889634f;   // log2(e)

// ---------------- K1: s = h @ W  (M=4096, K=256, N=256) ----------------
constexpr int BM = 64, BN = 64, BK = 32, ASTR = 36; // 36 words = 9x16B: float4-aligned rows

__global__ __launch_bounds__(256) void k_gemm(const float* __restrict__ hin,
                                              const float* __restrict__ W,
                                              float* __restrict__ s) {
    __shared__ float As[BM * ASTR];
    __shared__ float Bs[BK * BN];
    const int t = threadIdx.x;
    const int row0 = blockIdx.y * BM;
    const int col0 = blockIdx.x * BN;
    const int tx = t & 15, ty = t >> 4;
    float acc[4][4] = {};
    for (int k0 = 0; k0 < Fin; k0 += BK) {
        #pragma unroll
        for (int v = t; v < BM * BK / 4; v += 256) {
            int r = v >> 3, k4 = v & 7;
            float4 av = *reinterpret_cast<const float4*>(
                &hin[(size_t)(row0 + r) * Fin + k0 + k4 * 4]);
            *reinterpret_cast<float4*>(&As[r * ASTR + k4 * 4]) = av;
        }
        #pragma unroll
        for (int v = t; v < BK * BN / 4; v += 256) {
            int kk = v >> 4, c4 = v & 15;
            *reinterpret_cast<float4*>(&Bs[kk * BN + c4 * 4]) =
                *reinterpret_cast<const float4*>(
                    &W[(size_t)(k0 + kk) * Cc + col0 + c4 * 4]);
        }
        __syncthreads();
        #pragma unroll
        for (int kq = 0; kq < BK / 4; ++kq) {
            float4 a0 = *reinterpret_cast<const float4*>(&As[(ty * 4 + 0) * ASTR + kq * 4]);
            float4 a1 = *reinterpret_cast<const float4*>(&As[(ty * 4 + 1) * ASTR + kq * 4]);
            float4 a2 = *reinterpret_cast<const float4*>(&As[(ty * 4 + 2) * ASTR + kq * 4]);
            float4 a3 = *reinterpret_cast<const float4*>(&As[(ty * 4 + 3) * ASTR + kq * 4]);
            float4 b0 = *reinterpret_cast<const float4*>(&Bs[(kq * 4 + 0) * BN + tx * 4]);
            float4 b1 = *reinterpret_cast<const float4*>(&Bs[(kq * 4 + 1) * BN + tx * 4]);
            float4 b2 = *reinterpret_cast<const float4*>(&Bs[(kq * 4 + 2) * BN + tx * 4]);
            float4 b3 = *reinterpret_cast<const float4*>(&Bs[(kq * 4 + 3) * BN + tx * 4]);
            float4 ar[4] = {a0, a1, a2, a3};
            #pragma unroll
            for (int i = 0; i < 4; ++i) {
                acc[i][0] = fmaf(ar[i].x, b0.x, acc[i][0]);
                acc[i][1] = fmaf(ar[i].x, b0.y, acc[i][1]);
                acc[i][2] = fmaf(ar[i].x, b0.z, acc[i][2]);
                acc[i][3] = fmaf(ar[i].x, b0.w, acc[i][3]);
                acc[i][0] = fmaf(ar[i].y, b1.x, acc[i][0]);
                acc[i][1] = fmaf(ar[i].y, b1.y, acc[i][1]);
                acc[i][2] = fmaf(ar[i].y, b1.z, acc[i][2]);
                acc[i][3] = fmaf(ar[i].y, b1.w, acc[i][3]);
                acc[i][0] = fmaf(ar[i].z, b2.x, acc[i][0]);
                acc[i][1] = fmaf(ar[i].z, b2.y, acc[i][1]);
                acc[i][2] = fmaf(ar[i].z, b2.z, acc[i][2]);
                acc[i][3] = fmaf(ar[i].z, b2.w, acc[i][3]);
                acc[i][0] = fmaf(ar[i].w, b3.x, acc[i][0]);
                acc[i][1] = fmaf(ar[i].w, b3.y, acc[i][1]);
                acc[i][2] = fmaf(ar[i].w, b3.z, acc[i][2]);
                acc[i][3] = fmaf(ar[i].w, b3.w, acc[i][3]);
            }
        }
        __syncthreads();
    }
    #pragma unroll
    for (int i = 0; i < 4; ++i) {
        float4 o = make_float4(acc[i][0], acc[i][1], acc[i][2], acc[i][3]);
        *reinterpret_cast<float4*>(
            &s[(size_t)(row0 + ty * 4 + i) * Cc + col0 + tx * 4]) = o;
    }
}

// ---------------- K2: e_i/e_j = (s . a_left/right) * log2(e) ----------------
__global__ void k_edge(const float* __restrict__ s, const float* __restrict__ av,
                       float* __restrict__ ei, float* __restrict__ ej) {
    const int idx = blockIdx.x * 256 + threadIdx.x;   // (b*N+n)*H + h
    const int hh = idx & 7;
    const int bn = idx >> 3;
    const float* sp = &s[(size_t)bn * Cc + hh * Hid];
    float si = 0.f, sj = 0.f;
    #pragma unroll
    for (int f4 = 0; f4 < 8; ++f4) {
        float4 sv = *reinterpret_cast<const float4*>(&sp[f4 * 4]);
        float4 al = *reinterpret_cast<const float4*>(&av[f4 * 4]);
        float4 ar = *reinterpret_cast<const float4*>(&av[Hid + f4 * 4]);
        si += sv.x * al.x + sv.y * al.y + sv.z * al.z + sv.w * al.w;
        sj += sv.x * ar.x + sv.y * ar.y + sv.z * ar.z + sv.w * ar.w;
    }
    ei[idx] = si * L2E;      // pre-scale: exp(x) == exp2(x*L2E); lrelu commutes with +scale
    ej[idx] = sj * L2E;
}

// ---------------- K3: column sums Z[b,j,h] + packed adjacency bitmask ----------------
__global__ __launch_bounds__(256) void k_colsum(const float* __restrict__ ei,
                                                const float* __restrict__ ej,
                                                const int* __restrict__ adj,
                                                float* __restrict__ Zp,
                                                unsigned long long* __restrict__ adjB) {
    const int chunk = blockIdx.x;          // 4 i-chunks of 256 rows
    const int jt = blockIdx.y;             // 16 column tiles of 64
    const int b = blockIdx.z;              // 4 batches
    const int i0 = chunk * 256;
    const int j0 = jt * 64;
    const int t = threadIdx.x;
    const int jj = t & 63;
    const int g = t >> 6;
    __shared__ float ei_s[256 * Hh];
    __shared__ float red[4 * 64 * Hh];
    for (int v = t; v < 256 * Hh; v += 256)
        ei_s[v] = ei[((size_t)b * Nn + i0) * Hh + v];
    float ejr[Hh];
    #pragma unroll
    for (int hh = 0; hh < Hh; ++hh)
        ejr[hh] = ej[((size_t)b * Nn + j0 + jj) * Hh + hh];
    __syncthreads();
    float z[Hh] = {};
    const int* ap = &adj[((size_t)b * Nn + i0 + g * 64) * Nn + j0 + jj];
    for (int it = 0; it < 64; ++it) {
        int a = ap[(size_t)it * Nn];       // coalesced 64-wide row read
        unsigned long long bal = __ballot(a != 0);     // pack 64 j-bits for row i
        if (jj == 0)
            adjB[((size_t)b * Nn + i0 + g * 64 + it) * 16 + jt] = bal;
        float mf = (float)a;
        const float* ep = &ei_s[(g * 64 + it) * Hh];
        #pragma unroll
        for (int hh = 0; hh < Hh; ++hh) {
            float x = ep[hh] + ejr[hh];
            x = fmaxf(x, Alpha * x);       // leaky relu
            z[hh] = fmaf(mf, exp2f(x), z[hh]);
        }
    }
    #pragma unroll
    for (int hh = 0; hh < Hh; ++hh)
        red[(g * 64 + jj) * Hh + hh] = z[hh];
    __syncthreads();
    for (int v = t; v < 64 * Hh; v += 256) {
        float sum = red[v] + red[512 + v] + red[1024 + v] + red[1536 + v];
        Zp[(size_t)chunk * (Bb * Nn * Hh) + ((size_t)b * Nn + j0) * Hh + v] = sum;
    }
}

// ---------------- K4: ezr[b,j,h] = {ej_scaled, 1/Z} ----------------
__global__ void k_ezr(const float* __restrict__ Zp, const float* __restrict__ ej,
                      float2* __restrict__ ezr) {
    const int idx = blockIdx.x * 256 + threadIdx.x;   // 32768
    constexpr int S = Bb * Nn * Hh;
    float sum = Zp[idx] + Zp[S + idx] + Zp[2 * S + idx] + Zp[3 * S + idx];
    ezr[idx] = make_float2(ej[idx], 1.0f / sum);
}

// ---------------- K5: partial aggregation, thread = (b,i,h), acc[32] over f ----------------
// grid (16,8,4): x = b*4+ic (256 rows per block), y = h, z = jc (j-chunk of 256)
__global__ __launch_bounds__(256) void k_agg(const float* __restrict__ s,
                                             const float* __restrict__ ei,
                                             const float2* __restrict__ ezr,
                                             const unsigned long long* __restrict__ adjB,
                                             float* __restrict__ part) {
    const int b  = blockIdx.x >> 2;
    const int ic = blockIdx.x & 3;
    const int h  = blockIdx.y;
    const int jc = blockIdx.z;
    const int i  = ic * 256 + threadIdx.x;

    const float ei_r = ei[((size_t)b * Nn + i) * Hh + h];
    const uint2* mp = reinterpret_cast<const uint2*>(
        &adjB[((size_t)b * Nn + i) * 16 + jc * 4]);
    const float*  sg = s   + ((size_t)b * Nn + jc * 256) * Cc + h * Hid;
    const float2* eg = ezr + ((size_t)b * Nn + jc * 256) * Hh + h;

    float acc[32] = {};

    #pragma unroll
    for (int jt = 0; jt < 4; ++jt) {
        uint2 m64 = mp[jt];
        #pragma unroll
        for (int half = 0; half < 2; ++half) {
            unsigned mm = half ? m64.y : m64.x;
            const int jb = jt * 64 + half * 32;
            #pragma unroll 4
            for (int jj = 0; jj < 32; ++jj) {
                const int j = jb + jj;
                float2 er = eg[(size_t)j * Hh];        // wave-uniform -> s_load
                float x = ei_r + er.x;
                x = fmaxf(x, Alpha * x);
                float w = exp2f(x) * er.y;
                w = (mm & 1u) ? w : 0.0f;
                mm >>= 1;
                const float4* sr = reinterpret_cast<const float4*>(sg + (size_t)j * Cc);
                #pragma unroll
                for (int q = 0; q < 8; ++q) {
                    float4 v = sr[q];                  // wave-uniform -> s_load_dwordx4
                    acc[q * 4 + 0] = fmaf(w, v.x, acc[q * 4 + 0]);
                    acc[q * 4 + 1] = fmaf(w, v.y, acc[q * 4 + 1]);
                    acc[q * 4 + 2] = fmaf(w, v.z, acc[q * 4 + 2]);
                    acc[q * 4 + 3] = fmaf(w, v.w, acc[q * 4 + 3]);
                }
            }
        }
    }
    float* pp = part + (size_t)jc * (Bb * Nn * Cc) + ((size_t)b * Nn + i) * Cc + h * Hid;
    #pragma unroll
    for (int q = 0; q < 8; ++q)
        *reinterpret_cast<float4*>(pp + q * 4) =
            make_float4(acc[q * 4 + 0], acc[q * 4 + 1], acc[q * 4 + 2], acc[q * 4 + 3]);
}

// ---------------- K6: out = sum of 4 partials + bias ----------------
__global__ void k_reduce(const float* __restrict__ part, const float* __restrict__ bias,
                         float* __restrict__ out) {
    const int idx = blockIdx.x * 256 + threadIdx.x;   // float4 index, 262144 total
    constexpr size_t S = (size_t)Bb * Nn * Cc / 4;
    const float4* p = reinterpret_cast<const float4*>(part);
    float4 v0 = p[idx], v1 = p[S + idx], v2 = p[2 * S + idx], v3 = p[3 * S + idx];
    float4 bv = reinterpret_cast<const float4*>(bias)[idx & 63];
    float4 o;
    o.x = v0.x + v1.x + v2.x + v3.x + bv.x;
    o.y = v0.y + v1.y + v2.y + v3.y + bv.y;
    o.z = v0.z + v1.z + v2.z + v3.z + bv.z;
    o.w = v0.w + v1.w + v2.w + v3.w + bv.w;
    reinterpret_cast<float4*>(out)[idx] = o;
}

extern "C" void kernel_launch(void* const* d_in, const int* in_sizes, int n_in,
                              void* d_out, int out_size, void* d_ws, size_t ws_size,
                              hipStream_t stream) {
    const float* hin  = (const float*)d_in[0];
    const int*   adj  = (const int*)d_in[1];
    const float* W    = (const float*)d_in[2];
    const float* a    = (const float*)d_in[3];
    const float* bias = (const float*)d_in[4];
    float* out = (float*)d_out;
    float* ws  = (float*)d_ws;

    float*  s    = ws;                         // 1,048,576 f32
    float*  ei   = ws + 1048576;               // 32,768
    float*  ej   = ws + 1081344;               // 32,768
    float*  Zp   = ws + 1114112;               // 131,072 (4 partials)
    float2* ezr  = (float2*)(ws + 1245184);    // 32,768 float2 (65,536 f32)
    unsigned long long* adjB = (unsigned long long*)(ws + 1310720);  // 65,536 u64
    float*  part = ws + 1441792;               // 4 x 1,048,576

    k_gemm  <<<dim3(Cc / BN, (Bb * Nn) / BM), 256, 0, stream>>>(hin, W, s);
    k_edge  <<<dim3((Bb * Nn * Hh) / 256),    256, 0, stream>>>(s, a, ei, ej);
    k_colsum<<<dim3(4, 16, 4),                256, 0, stream>>>(ei, ej, adj, Zp, adjB);
    k_ezr   <<<dim3((Bb * Nn * Hh) / 256),    256, 0, stream>>>(Zp, ej, ezr);
    k_agg   <<<dim3(16, 8, 4),                256, 0, stream>>>(s, ei, ezr, adjB, part);
    k_reduce<<<dim3((Bb * Nn * Cc) / 1024),   256, 0, stream>>>(part, bias, out);
}

// Round 3
// 151.613 us; speedup vs baseline: 1.6170x; 1.6170x over previous
//
#include <hip/hip_runtime.h>
#include <hip/hip_bf16.h>

constexpr int Bb  = 4;
constexpr int Nn  = 1024;
constexpr int Fin = 256;
constexpr int Cc  = 256;   // H*HID
constexpr int Hh  = 8;
constexpr int Hid = 32;
constexpr float Alpha = 0.2f;
constexpr float L2E = 1.4426950408889634f;   // log2(e)

typedef __attribute__((ext_vector_type(8))) short bf16x8;
typedef __attribute__((ext_vector_type(4))) float f32x4;

__device__ __forceinline__ unsigned short f2b(float f) {   // f32 -> bf16 RNE
    unsigned u = __float_as_uint(f);
    u += 0x7FFFu + ((u >> 16) & 1u);
    return (unsigned short)(u >> 16);
}

// ---------------- K1: s = h @ W  (f32; A-reads bank-clean via strided rows + XOR slot swizzle) ----
constexpr int BM = 64, BN = 64, BK = 32;

__global__ __launch_bounds__(256) void k_gemm(const float* __restrict__ hin,
                                              const float* __restrict__ W,
                                              float* __restrict__ s) {
    __shared__ float As[BM * BK];   // row-major 32 words/row, k-quad slots XOR-swizzled by row&7
    __shared__ float Bs[BK * BN];
    const int t = threadIdx.x;
    const int row0 = blockIdx.y * BM;
    const int col0 = blockIdx.x * BN;
    const int tx = t & 15, ty = t >> 4;
    float acc[4][4] = {};
    for (int k0 = 0; k0 < Fin; k0 += BK) {
        #pragma unroll
        for (int v = t; v < BM * BK / 4; v += 256) {
            int r = v >> 3, k4 = v & 7;
            float4 av = *reinterpret_cast<const float4*>(
                &hin[(size_t)(row0 + r) * Fin + k0 + k4 * 4]);
            *reinterpret_cast<float4*>(&As[r * 32 + ((k4 ^ (r & 7)) << 2)]) = av;
        }
        #pragma unroll
        for (int v = t; v < BK * BN / 4; v += 256) {
            int kk = v >> 4, c4 = v & 15;
            *reinterpret_cast<float4*>(&Bs[kk * BN + c4 * 4]) =
                *reinterpret_cast<const float4*>(
                    &W[(size_t)(k0 + kk) * Cc + col0 + c4 * 4]);
        }
        __syncthreads();
        #pragma unroll
        for (int kq = 0; kq < BK / 4; ++kq) {
            const int slot = (kq ^ (ty & 7)) << 2;
            float4 am[4];
            #pragma unroll
            for (int m = 0; m < 4; ++m)
                am[m] = *reinterpret_cast<const float4*>(&As[(ty + 16 * m) * 32 + slot]);
            float4 bk[4];
            #pragma unroll
            for (int kk = 0; kk < 4; ++kk)
                bk[kk] = *reinterpret_cast<const float4*>(&Bs[(kq * 4 + kk) * BN + tx * 4]);
            #pragma unroll
            for (int m = 0; m < 4; ++m) {
                acc[m][0] = fmaf(am[m].x, bk[0].x, acc[m][0]);
                acc[m][1] = fmaf(am[m].x, bk[0].y, acc[m][1]);
                acc[m][2] = fmaf(am[m].x, bk[0].z, acc[m][2]);
                acc[m][3] = fmaf(am[m].x, bk[0].w, acc[m][3]);
                acc[m][0] = fmaf(am[m].y, bk[1].x, acc[m][0]);
                acc[m][1] = fmaf(am[m].y, bk[1].y, acc[m][1]);
                acc[m][2] = fmaf(am[m].y, bk[1].z, acc[m][2]);
                acc[m][3] = fmaf(am[m].y, bk[1].w, acc[m][3]);
                acc[m][0] = fmaf(am[m].z, bk[2].x, acc[m][0]);
                acc[m][1] = fmaf(am[m].z, bk[2].y, acc[m][1]);
                acc[m][2] = fmaf(am[m].z, bk[2].z, acc[m][2]);
                acc[m][3] = fmaf(am[m].z, bk[2].w, acc[m][3]);
                acc[m][0] = fmaf(am[m].w, bk[3].x, acc[m][0]);
                acc[m][1] = fmaf(am[m].w, bk[3].y, acc[m][1]);
                acc[m][2] = fmaf(am[m].w, bk[3].z, acc[m][2]);
                acc[m][3] = fmaf(am[m].w, bk[3].w, acc[m][3]);
            }
        }
        __syncthreads();
    }
    #pragma unroll
    for (int m = 0; m < 4; ++m) {
        float4 o = make_float4(acc[m][0], acc[m][1], acc[m][2], acc[m][3]);
        *reinterpret_cast<float4*>(
            &s[(size_t)(row0 + ty + 16 * m) * Cc + col0 + tx * 4]) = o;
    }
}

// ---------------- K2: e_i/e_j = (s . a_left/right) * log2(e) ----------------
__global__ void k_edge(const float* __restrict__ s, const float* __restrict__ av,
                       float* __restrict__ ei, float* __restrict__ ej) {
    const int idx = blockIdx.x * 256 + threadIdx.x;   // (b*N+n)*H + h
    const int hh = idx & 7;
    const int bn = idx >> 3;
    const float* sp = &s[(size_t)bn * Cc + hh * Hid];
    float si = 0.f, sj = 0.f;
    #pragma unroll
    for (int f4 = 0; f4 < 8; ++f4) {
        float4 sv = *reinterpret_cast<const float4*>(&sp[f4 * 4]);
        float4 al = *reinterpret_cast<const float4*>(&av[f4 * 4]);
        float4 ar = *reinterpret_cast<const float4*>(&av[Hid + f4 * 4]);
        si += sv.x * al.x + sv.y * al.y + sv.z * al.z + sv.w * al.w;
        sj += sv.x * ar.x + sv.y * ar.y + sv.z * ar.z + sv.w * ar.w;
    }
    ei[idx] = si * L2E;
    ej[idx] = sj * L2E;
}

// ---------------- K3: column sums Z[b,j,h] + transposed adjacency bitmask ----------------
__global__ __launch_bounds__(256) void k_colsum(const float* __restrict__ ei,
                                                const float* __restrict__ ej,
                                                const int* __restrict__ adj,
                                                float* __restrict__ Zp,
                                                unsigned long long* __restrict__ adjBT) {
    const int chunk = blockIdx.x;          // 4 i-chunks of 256 rows
    const int jt = blockIdx.y;             // 16 column tiles of 64
    const int b = blockIdx.z;
    const int i0 = chunk * 256;
    const int j0 = jt * 64;
    const int t = threadIdx.x;
    const int jj = t & 63;
    const int g = t >> 6;                  // wave id
    __shared__ float ei_s[256 * Hh];
    __shared__ float red[4 * 64 * Hh];
    for (int v = t; v < 256 * Hh; v += 256)
        ei_s[v] = ei[((size_t)b * Nn + i0) * Hh + v];
    float ejr[Hh];
    #pragma unroll
    for (int hh = 0; hh < Hh; ++hh)
        ejr[hh] = ej[((size_t)b * Nn + j0 + jj) * Hh + hh];
    __syncthreads();
    float z[Hh] = {};
    const int* ap = &adj[((size_t)b * Nn + i0 + g * 64) * Nn + j0 + jj];
    for (int it = 0; it < 64; ++it) {
        int a = ap[(size_t)it * Nn];
        unsigned long long bal = __ballot(a != 0);     // bit jj <-> column j0+jj of row i
        if (jj == 0)
            adjBT[((size_t)b * 16 + jt) * Nn + (i0 + g * 64 + it)] = bal;
        float mf = (float)a;
        const float* ep = &ei_s[(g * 64 + it) * Hh];   // wave-broadcast
        #pragma unroll
        for (int hh = 0; hh < Hh; ++hh) {
            float x = ep[hh] + ejr[hh];
            x = fmaxf(x, Alpha * x);
            z[hh] = fmaf(mf, exp2f(x), z[hh]);
        }
    }
    #pragma unroll
    for (int hh = 0; hh < Hh; ++hh)
        red[(g * 64 + jj) * Hh + hh] = z[hh];
    __syncthreads();
    for (int v = t; v < 64 * Hh; v += 256) {
        float sum = red[v] + red[512 + v] + red[1024 + v] + red[1536 + v];
        Zp[(size_t)chunk * (Bb * Nn * Hh) + ((size_t)b * Nn + j0) * Hh + v] = sum;
    }
}

// ---------------- K4: transposed per-(b,h) tables: eiT[bh][i], ezrT[bh][j]={ej,1/Z} --------
__global__ void k_ezrT(const float* __restrict__ Zp, const float* __restrict__ ei,
                       const float* __restrict__ ej,
                       float* __restrict__ eiT, float2* __restrict__ ezrT) {
    const int tid = blockIdx.x * 256 + threadIdx.x;   // 32768: [b][h][n]
    const int n = tid & 1023;
    const int bh = tid >> 10;
    const int b = bh >> 3, h = bh & 7;
    const int src = (b * Nn + n) * Hh + h;
    constexpr int S = Bb * Nn * Hh;
    float sum = Zp[src] + Zp[S + src] + Zp[2 * S + src] + Zp[3 * S + src];
    ezrT[tid] = make_float2(ej[src], 1.0f / sum);
    eiT[tid] = ei[src];
}

// ---------------- K5: pack s -> bf16 MFMA-B-fragment order ----------------
// sB[bh][jt][fh][lane][e] : lane l holds col f=fh*16+(l&15), k-elems j=jt*32+(l>>4)*8+e
__global__ __launch_bounds__(256) void k_pack(const float* __restrict__ s,
                                              unsigned short* __restrict__ sB) {
    const int tid = blockIdx.x * 256 + threadIdx.x;   // 131072
    const int l  = tid & 63;
    const int fh = (tid >> 6) & 1;
    const int jt = (tid >> 7) & 31;
    const int bh = tid >> 12;
    const int b = bh >> 3, h = bh & 7;
    const int j = jt * 32 + (l >> 4) * 8;
    const int f = fh * 16 + (l & 15);
    const float* sp = &s[((size_t)b * Nn + j) * Cc + h * Hid + f];
    unsigned short u[8];
    #pragma unroll
    for (int e = 0; e < 8; ++e)
        u[e] = f2b(sp[(size_t)e * Cc]);
    ushort4* dst = reinterpret_cast<ushort4*>(
        &sB[(size_t)bh * 32768 + jt * 1024 + fh * 512 + l * 8]);
    dst[0] = make_ushort4(u[0], u[1], u[2], u[3]);
    dst[1] = make_ushort4(u[4], u[5], u[6], u[7]);
}

// ---------------- K6: MFMA aggregation: out = (E.rz) @ s_bf16 + bias ----------------
// grid 512 flat; decode keeps all 16 i-tiles of a (b,h) on one XCD for sB L2 reuse.
__global__ __launch_bounds__(256) void k_agg(const unsigned short* __restrict__ sB,
                                             const float* __restrict__ eiT,
                                             const float2* __restrict__ ezrT,
                                             const unsigned long long* __restrict__ adjBT,
                                             const float* __restrict__ bias,
                                             float* __restrict__ out) {
    const int bid = blockIdx.x;
    const int xcd = bid & 7, g = bid >> 3;
    const int bh = xcd * 4 + (g & 3);
    const int it = g >> 2;
    const int b = bh >> 3, h = bh & 7;
    const int t = threadIdx.x, w = t >> 6, l = t & 63;
    const int lg = l >> 4;                 // k-group 0..3
    const int row = it * 64 + w * 16 + (l & 15);   // A-fragment row
    const float ei_r = eiT[bh * Nn + row];

    const float4* ez4 = reinterpret_cast<const float4*>(ezrT + (size_t)bh * Nn);
    const unsigned short* sbp = sB + (size_t)bh * 32768;

    f32x4 acc0 = {0.f, 0.f, 0.f, 0.f}, acc1 = {0.f, 0.f, 0.f, 0.f};

    for (int jk = 0; jk < 32; ++jk) {
        const int j8 = jk * 32 + lg * 8;
        float4 za = ez4[(j8 >> 1) + 0];    // {ej0,rz0,ej1,rz1}
        float4 zb = ez4[(j8 >> 1) + 1];
        float4 zc = ez4[(j8 >> 1) + 2];
        float4 zd = ez4[(j8 >> 1) + 3];
        unsigned long long m64 = adjBT[((size_t)b * 16 + (jk >> 1)) * Nn + row];
        unsigned mb = (unsigned)(m64 >> ((jk & 1) * 32 + lg * 8)) & 0xFFu;

        float wv[8];
        {
            float ejv[8] = {za.x, za.z, zb.x, zb.z, zc.x, zc.z, zd.x, zd.z};
            float rzv[8] = {za.y, za.w, zb.y, zb.w, zc.y, zc.w, zd.y, zd.w};
            #pragma unroll
            for (int e = 0; e < 8; ++e) {
                float x = ei_r + ejv[e];
                x = fmaxf(x, Alpha * x);
                float ww = exp2f(x) * rzv[e];
                wv[e] = ((mb >> e) & 1u) ? ww : 0.0f;
            }
        }
        union { bf16x8 v; unsigned short us[8]; } A;
        #pragma unroll
        for (int e = 0; e < 8; ++e) A.us[e] = f2b(wv[e]);

        bf16x8 b0 = *reinterpret_cast<const bf16x8*>(sbp + (size_t)jk * 1024 + l * 8);
        bf16x8 b1 = *reinterpret_cast<const bf16x8*>(sbp + (size_t)jk * 1024 + 512 + l * 8);

        acc0 = __builtin_amdgcn_mfma_f32_16x16x32_bf16(A.v, b0, acc0, 0, 0, 0);
        acc1 = __builtin_amdgcn_mfma_f32_16x16x32_bf16(A.v, b1, acc1, 0, 0, 0);
    }

    const int col = l & 15;
    const float bv0 = bias[h * Hid + col];
    const float bv1 = bias[h * Hid + 16 + col];
    const int r0 = it * 64 + w * 16 + lg * 4;      // C rows: (l>>4)*4 + reg
    #pragma unroll
    for (int reg = 0; reg < 4; ++reg) {
        float* op = &out[((size_t)b * Nn + r0 + reg) * Cc + h * Hid];
        op[col]      = acc0[reg] + bv0;
        op[16 + col] = acc1[reg] + bv1;
    }
}

extern "C" void kernel_launch(void* const* d_in, const int* in_sizes, int n_in,
                              void* d_out, int out_size, void* d_ws, size_t ws_size,
                              hipStream_t stream) {
    const float* hin  = (const float*)d_in[0];
    const int*   adj  = (const int*)d_in[1];
    const float* W    = (const float*)d_in[2];
    const float* a    = (const float*)d_in[3];
    const float* bias = (const float*)d_in[4];
    float* out = (float*)d_out;
    float* ws  = (float*)d_ws;

    float*  s    = ws;                                    // 1,048,576
    float*  ei   = ws + 1048576;                          // 32,768
    float*  ej   = ws + 1081344;                          // 32,768
    float*  Zp   = ws + 1114112;                          // 131,072
    float*  eiT  = ws + 1245184;                          // 32,768
    float2* ezrT = (float2*)(ws + 1277952);               // 32,768 float2
    unsigned long long* adjBT = (unsigned long long*)(ws + 1343488); // 65,536 u64
    unsigned short* sB = (unsigned short*)(ws + 1474560); // 1,048,576 bf16

    k_gemm  <<<dim3(Cc / BN, (Bb * Nn) / BM), 256, 0, stream>>>(hin, W, s);
    k_edge  <<<dim3((Bb * Nn * Hh) / 256),    256, 0, stream>>>(s, a, ei, ej);
    k_colsum<<<dim3(4, 16, 4),                256, 0, stream>>>(ei, ej, adj, Zp, adjBT);
    k_ezrT  <<<dim3((Bb * Nn * Hh) / 256),    256, 0, stream>>>(Zp, ei, ej, eiT, ezrT);
    k_pack  <<<dim3(512),                     256, 0, stream>>>(s, sB);
    k_agg   <<<dim3(512),                     256, 0, stream>>>(sB, eiT, ezrT, adjBT, bias, out);
}

// Round 6
// 132.003 us; speedup vs baseline: 1.8573x; 1.1486x over previous
//
#include <hip/hip_runtime.h>
#include <hip/hip_bf16.h>

constexpr int Bb  = 4;
constexpr int Nn  = 1024;
constexpr int Fin = 256;
constexpr int Cc  = 256;   // H*HID
constexpr int Hh  = 8;
constexpr int Hid = 32;
constexpr float Alpha = 0.2f;
constexpr float L2E = 1.4426950408889634f;   // log2(e)
constexpr int NCHUNK = 16;                   // i-chunks for colsum partials

typedef __attribute__((ext_vector_type(8))) short bf16x8;
typedef __attribute__((ext_vector_type(4))) float f32x4;

__device__ __forceinline__ unsigned cvt_pk_bf16(float lo, float hi) {
    unsigned r;
    asm("v_cvt_pk_bf16_f32 %0, %1, %2" : "=v"(r) : "v"(lo), "v"(hi));
    return r;
}

// ---------------- K1: s = h @ W  (f32; A-reads bank-clean via strided rows + XOR slot swizzle) ----
constexpr int BM = 64, BN = 64, BK = 32;

__global__ __launch_bounds__(256) void k_gemm(const float* __restrict__ hin,
                                              const float* __restrict__ W,
                                              float* __restrict__ s) {
    __shared__ float As[BM * BK];   // row-major 32 words/row, k-quad slots XOR-swizzled by row&7
    __shared__ float Bs[BK * BN];
    const int t = threadIdx.x;
    const int row0 = blockIdx.y * BM;
    const int col0 = blockIdx.x * BN;
    const int tx = t & 15, ty = t >> 4;
    float acc[4][4] = {};
    for (int k0 = 0; k0 < Fin; k0 += BK) {
        #pragma unroll
        for (int v = t; v < BM * BK / 4; v += 256) {
            int r = v >> 3, k4 = v & 7;
            float4 av = *reinterpret_cast<const float4*>(
                &hin[(size_t)(row0 + r) * Fin + k0 + k4 * 4]);
            *reinterpret_cast<float4*>(&As[r * 32 + ((k4 ^ (r & 7)) << 2)]) = av;
        }
        #pragma unroll
        for (int v = t; v < BK * BN / 4; v += 256) {
            int kk = v >> 4, c4 = v & 15;
            *reinterpret_cast<float4*>(&Bs[kk * BN + c4 * 4]) =
                *reinterpret_cast<const float4*>(
                    &W[(size_t)(k0 + kk) * Cc + col0 + c4 * 4]);
        }
        __syncthreads();
        #pragma unroll
        for (int kq = 0; kq < BK / 4; ++kq) {
            const int slot = (kq ^ (ty & 7)) << 2;
            float4 am[4];
            #pragma unroll
            for (int m = 0; m < 4; ++m)
                am[m] = *reinterpret_cast<const float4*>(&As[(ty + 16 * m) * 32 + slot]);
            float4 bk[4];
            #pragma unroll
            for (int kk = 0; kk < 4; ++kk)
                bk[kk] = *reinterpret_cast<const float4*>(&Bs[(kq * 4 + kk) * BN + tx * 4]);
            #pragma unroll
            for (int m = 0; m < 4; ++m) {
                acc[m][0] = fmaf(am[m].x, bk[0].x, acc[m][0]);
                acc[m][1] = fmaf(am[m].x, bk[0].y, acc[m][1]);
                acc[m][2] = fmaf(am[m].x, bk[0].z, acc[m][2]);
                acc[m][3] = fmaf(am[m].x, bk[0].w, acc[m][3]);
                acc[m][0] = fmaf(am[m].y, bk[1].x, acc[m][0]);
                acc[m][1] = fmaf(am[m].y, bk[1].y, acc[m][1]);
                acc[m][2] = fmaf(am[m].y, bk[1].z, acc[m][2]);
                acc[m][3] = fmaf(am[m].y, bk[1].w, acc[m][3]);
                acc[m][0] = fmaf(am[m].z, bk[2].x, acc[m][0]);
                acc[m][1] = fmaf(am[m].z, bk[2].y, acc[m][1]);
                acc[m][2] = fmaf(am[m].z, bk[2].z, acc[m][2]);
                acc[m][3] = fmaf(am[m].z, bk[2].w, acc[m][3]);
                acc[m][0] = fmaf(am[m].w, bk[3].x, acc[m][0]);
                acc[m][1] = fmaf(am[m].w, bk[3].y, acc[m][1]);
                acc[m][2] = fmaf(am[m].w, bk[3].z, acc[m][2]);
                acc[m][3] = fmaf(am[m].w, bk[3].w, acc[m][3]);
            }
        }
        __syncthreads();
    }
    #pragma unroll
    for (int m = 0; m < 4; ++m) {
        float4 o = make_float4(acc[m][0], acc[m][1], acc[m][2], acc[m][3]);
        *reinterpret_cast<float4*>(
            &s[(size_t)(row0 + ty + 16 * m) * Cc + col0 + tx * 4]) = o;
    }
}

// ---------------- K2: e_i/e_j = (s . a_left/right) * log2(e) ----------------
__global__ void k_edge(const float* __restrict__ s, const float* __restrict__ av,
                       float* __restrict__ ei, float* __restrict__ ej) {
    const int idx = blockIdx.x * 256 + threadIdx.x;   // (b*N+n)*H + h
    const int hh = idx & 7;
    const int bn = idx >> 3;
    const float* sp = &s[(size_t)bn * Cc + hh * Hid];
    float si = 0.f, sj = 0.f;
    #pragma unroll
    for (int f4 = 0; f4 < 8; ++f4) {
        float4 sv = *reinterpret_cast<const float4*>(&sp[f4 * 4]);
        float4 al = *reinterpret_cast<const float4*>(&av[f4 * 4]);
        float4 ar = *reinterpret_cast<const float4*>(&av[Hid + f4 * 4]);
        si += sv.x * al.x + sv.y * al.y + sv.z * al.z + sv.w * al.w;
        sj += sv.x * ar.x + sv.y * ar.y + sv.z * ar.z + sv.w * ar.w;
    }
    ei[idx] = si * L2E;
    ej[idx] = sj * L2E;
}

// ---------------- K3: column sums Z[b,j,h] + transposed adjacency bitmask ----------------
// grid (16 ic, 16 jt, 4 b) = 1024 blocks (4/CU), wave handles 16 rows -> latency hidden.
__global__ __launch_bounds__(256) void k_colsum(const float* __restrict__ ei,
                                                const float* __restrict__ ej,
                                                const int* __restrict__ adj,
                                                float* __restrict__ Zp,
                                                unsigned long long* __restrict__ adjBT) {
    const int ic = blockIdx.x;             // 16 i-chunks of 64 rows
    const int jt = blockIdx.y;             // 16 column tiles of 64
    const int b  = blockIdx.z;
    const int i0 = ic * 64;
    const int j0 = jt * 64;
    const int t = threadIdx.x;
    const int jj = t & 63;
    const int g = t >> 6;                  // wave id, rows g*16..g*16+15
    __shared__ float eis[64 * Hh];         // 2 KB
    __shared__ float red[4 * 64 * Hh];     // 8 KB
    for (int v = t; v < 64 * Hh; v += 256)
        eis[v] = ei[((size_t)b * Nn + i0) * Hh + v];
    float ejr[Hh];
    {
        float4 eA = *reinterpret_cast<const float4*>(&ej[((size_t)b * Nn + j0 + jj) * Hh]);
        float4 eB = *reinterpret_cast<const float4*>(&ej[((size_t)b * Nn + j0 + jj) * Hh + 4]);
        ejr[0] = eA.x; ejr[1] = eA.y; ejr[2] = eA.z; ejr[3] = eA.w;
        ejr[4] = eB.x; ejr[5] = eB.y; ejr[6] = eB.z; ejr[7] = eB.w;
    }
    __syncthreads();
    float z[Hh] = {};
    const int* ap = &adj[((size_t)b * Nn + i0 + g * 16) * Nn + j0 + jj];
    #pragma unroll 4
    for (int ii = 0; ii < 16; ++ii) {
        int a = ap[(size_t)ii * Nn];
        unsigned long long bal = __ballot(a != 0);     // bit jj <-> column j0+jj of row i
        if (jj == 0)
            adjBT[((size_t)b * 16 + jt) * Nn + (i0 + g * 16 + ii)] = bal;
        float mf = (float)(a != 0);
        const float* ep = &eis[(g * 16 + ii) * Hh];    // wave-broadcast ds_read
        #pragma unroll
        for (int hh = 0; hh < Hh; ++hh) {
            float x = ep[hh] + ejr[hh];
            x = fmaxf(x, Alpha * x);
            z[hh] = fmaf(mf, exp2f(x), z[hh]);
        }
    }
    #pragma unroll
    for (int hh = 0; hh < Hh; ++hh)
        red[(g * 64 + jj) * Hh + hh] = z[hh];
    __syncthreads();
    for (int v = t; v < 64 * Hh; v += 256) {
        float sum = red[v] + red[512 + v] + red[1024 + v] + red[1536 + v];
        Zp[(size_t)ic * (Bb * Nn * Hh) + ((size_t)b * Nn + j0) * Hh + v] = sum;
    }
}

// ---------------- K4: transposed per-(b,h) tables: eiT[bh][i], ezrT[bh][j]={ej,1/Z} --------
__global__ void k_ezrT(const float* __restrict__ Zp, const float* __restrict__ ei,
                       const float* __restrict__ ej,
                       float* __restrict__ eiT, float2* __restrict__ ezrT) {
    const int tid = blockIdx.x * 256 + threadIdx.x;   // 32768: [b][h][n]
    const int n = tid & 1023;
    const int bh = tid >> 10;
    const int b = bh >> 3, h = bh & 7;
    const int src = (b * Nn + n) * Hh + h;
    constexpr int S = Bb * Nn * Hh;
    float sum = 0.f;
    #pragma unroll
    for (int c = 0; c < NCHUNK; ++c) sum += Zp[(size_t)c * S + src];
    ezrT[tid] = make_float2(ej[src], 1.0f / sum);
    eiT[tid] = ei[src];
}

// ---------------- K5: pack s -> bf16 MFMA-B-fragment order ----------------
// sB[bh][jt][fh][lane][e] : lane l holds col f=fh*16+(l&15), k-elems j=jt*32+(l>>4)*8+e
__global__ __launch_bounds__(256) void k_pack(const float* __restrict__ s,
                                              unsigned short* __restrict__ sB) {
    const int tid = blockIdx.x * 256 + threadIdx.x;   // 131072
    const int l  = tid & 63;
    const int fh = (tid >> 6) & 1;
    const int jt = (tid >> 7) & 31;
    const int bh = tid >> 12;
    const int b = bh >> 3, h = bh & 7;
    const int j = jt * 32 + (l >> 4) * 8;
    const int f = fh * 16 + (l & 15);
    const float* sp = &s[((size_t)b * Nn + j) * Cc + h * Hid + f];
    float v[8];
    #pragma unroll
    for (int e = 0; e < 8; ++e) v[e] = sp[(size_t)e * Cc];
    uint4 pk;
    pk.x = cvt_pk_bf16(v[0], v[1]);
    pk.y = cvt_pk_bf16(v[2], v[3]);
    pk.z = cvt_pk_bf16(v[4], v[5]);
    pk.w = cvt_pk_bf16(v[6], v[7]);
    *reinterpret_cast<uint4*>(&sB[(size_t)bh * 32768 + jt * 1024 + fh * 512 + l * 8]) = pk;
}

// ---------------- K6: MFMA aggregation: out = (E.rz) @ s_bf16 + bias ----------------
// grid 512 flat; decode keeps all 16 i-tiles of a (b,h) on one XCD for sB L2 reuse.
__global__ __launch_bounds__(256) void k_agg(const unsigned short* __restrict__ sB,
                                             const float* __restrict__ eiT,
                                             const float2* __restrict__ ezrT,
                                             const unsigned long long* __restrict__ adjBT,
                                             const float* __restrict__ bias,
                                             float* __restrict__ out) {
    const int bid = blockIdx.x;
    const int xcd = bid & 7, g = bid >> 3;
    const int bh = xcd * 4 + (g & 3);
    const int it = g >> 2;
    const int b = bh >> 3, h = bh & 7;
    const int t = threadIdx.x, w = t >> 6, l = t & 63;
    const int lg = l >> 4;                 // k-group 0..3
    const int row = it * 64 + w * 16 + (l & 15);   // A-fragment row
    const float ei_r = eiT[bh * Nn + row];

    const float4* ez4 = reinterpret_cast<const float4*>(ezrT + (size_t)bh * Nn);
    const unsigned short* sbp = sB + (size_t)bh * 32768;

    f32x4 acc0 = {0.f, 0.f, 0.f, 0.f}, acc1 = {0.f, 0.f, 0.f, 0.f};

    for (int jk = 0; jk < 32; ++jk) {
        const int j8 = jk * 32 + lg * 8;
        float4 za = ez4[(j8 >> 1) + 0];    // {ej0,rz0,ej1,rz1}
        float4 zb = ez4[(j8 >> 1) + 1];
        float4 zc = ez4[(j8 >> 1) + 2];
        float4 zd = ez4[(j8 >> 1) + 3];
        unsigned long long m64 = adjBT[((size_t)b * 16 + (jk >> 1)) * Nn + row];
        unsigned mb = (unsigned)(m64 >> ((jk & 1) * 32 + lg * 8)) & 0xFFu;

        float wv[8];
        {
            float ejv[8] = {za.x, za.z, zb.x, zb.z, zc.x, zc.z, zd.x, zd.z};
            float rzv[8] = {za.y, za.w, zb.y, zb.w, zc.y, zc.w, zd.y, zd.w};
            #pragma unroll
            for (int e = 0; e < 8; ++e) {
                float x = ei_r + ejv[e];
                x = fmaxf(x, Alpha * x);
                float ww = exp2f(x) * rzv[e];
                wv[e] = ((mb >> e) & 1u) ? ww : 0.0f;
            }
        }
        union { bf16x8 v; unsigned u[4]; } A;
        A.u[0] = cvt_pk_bf16(wv[0], wv[1]);
        A.u[1] = cvt_pk_bf16(wv[2], wv[3]);
        A.u[2] = cvt_pk_bf16(wv[4], wv[5]);
        A.u[3] = cvt_pk_bf16(wv[6], wv[7]);

        bf16x8 b0 = *reinterpret_cast<const bf16x8*>(sbp + (size_t)jk * 1024 + l * 8);
        bf16x8 b1 = *reinterpret_cast<const bf16x8*>(sbp + (size_t)jk * 1024 + 512 + l * 8);

        acc0 = __builtin_amdgcn_mfma_f32_16x16x32_bf16(A.v, b0, acc0, 0, 0, 0);
        acc1 = __builtin_amdgcn_mfma_f32_16x16x32_bf16(A.v, b1, acc1, 0, 0, 0);
    }

    const int col = l & 15;
    const float bv0 = bias[h * Hid + col];
    const float bv1 = bias[h * Hid + 16 + col];
    const int r0 = it * 64 + w * 16 + lg * 4;      // C rows: (l>>4)*4 + reg
    #pragma unroll
    for (int reg = 0; reg < 4; ++reg) {
        float* op = &out[((size_t)b * Nn + r0 + reg) * Cc + h * Hid];
        op[col]      = acc0[reg] + bv0;
        op[16 + col] = acc1[reg] + bv1;
    }
}

extern "C" void kernel_launch(void* const* d_in, const int* in_sizes, int n_in,
                              void* d_out, int out_size, void* d_ws, size_t ws_size,
                              hipStream_t stream) {
    const float* hin  = (const float*)d_in[0];
    const int*   adj  = (const int*)d_in[1];
    const float* W    = (const float*)d_in[2];
    const float* a    = (const float*)d_in[3];
    const float* bias = (const float*)d_in[4];
    float* out = (float*)d_out;
    float* ws  = (float*)d_ws;

    float*  s    = ws;                                    // 1,048,576
    float*  ei   = ws + 1048576;                          // 32,768
    float*  ej   = ws + 1081344;                          // 32,768
    float*  Zp   = ws + 1114112;                          // 16 x 32,768
    float*  eiT  = ws + 1638400;                          // 32,768
    float2* ezrT = (float2*)(ws + 1671168);               // 32,768 float2
    unsigned long long* adjBT = (unsigned long long*)(ws + 1736704); // 65,536 u64
    unsigned short* sB = (unsigned short*)(ws + 1867776); // 1,048,576 bf16

    k_gemm  <<<dim3(Cc / BN, (Bb * Nn) / BM), 256, 0, stream>>>(hin, W, s);
    k_edge  <<<dim3((Bb * Nn * Hh) / 256),    256, 0, stream>>>(s, a, ei, ej);
    k_colsum<<<dim3(16, 16, 4),               256, 0, stream>>>(ei, ej, adj, Zp, adjBT);
    k_ezrT  <<<dim3((Bb * Nn * Hh) / 256),    256, 0, stream>>>(Zp, ei, ej, eiT, ezrT);
    k_pack  <<<dim3(512),                     256, 0, stream>>>(s, sB);
    k_agg   <<<dim3(512),                     256, 0, stream>>>(sB, eiT, ezrT, adjBT, bias, out);
}

// Round 7
// 115.323 us; speedup vs baseline: 2.1259x; 1.1446x over previous
//
#include <hip/hip_runtime.h>
#include <hip/hip_bf16.h>

constexpr int Bb  = 4;
constexpr int Nn  = 1024;
constexpr int Fin = 256;
constexpr int Cc  = 256;   // H*HID
constexpr int Hh  = 8;
constexpr int Hid = 32;
constexpr float Alpha = 0.2f;
constexpr float L2E = 1.4426950408889634f;   // log2(e)
constexpr int NCHUNK = 16;                   // i-chunks for colsum partials

typedef __attribute__((ext_vector_type(8))) short bf16x8;
typedef __attribute__((ext_vector_type(4))) float f32x4;

__device__ __forceinline__ unsigned cvt_pk_bf16(float lo, float hi) {
    unsigned r;
    asm("v_cvt_pk_bf16_f32 %0, %1, %2" : "=v"(r) : "v"(lo), "v"(hi));
    return r;
}

// ---------------- K1: fused s = h @ W (bf16 MFMA) + ei/ej dots + sC fragment store ----
// grid (4 head-pairs, 64 row-tiles), 256 thr. LDS: A 64x256 bf16 + B(W^T) 64x256 bf16,
// both with 16B-quad XOR swizzle (quad ^ ((row>>1)&7)) -> 2-way conflicts (free).
// sC layout [bh][jt16=64][fh=2][lane=64][reg=4] bf16: wave stores 512B coalesced.
__global__ __launch_bounds__(256) void k_gemm(const float* __restrict__ hin,
                                              const float* __restrict__ W,
                                              const float* __restrict__ av,
                                              float* __restrict__ eiT,
                                              float* __restrict__ ejT,
                                              unsigned short* __restrict__ sC) {
    __shared__ unsigned short Asm[64 * 256];
    __shared__ unsigned short Bsm[64 * 256];
    const int t = threadIdx.x;
    const int hp = blockIdx.x;        // head-pair 0..3 (cols hp*64)
    const int rt = blockIdx.y;        // row tile 0..63
    const int b = rt >> 4;
    const int row0m = (rt & 15) * 64; // row within batch
    const int grow0 = rt * 64;        // global M row
    const int col0 = hp * 64;

    // stage A: h[grow0..+64][0..256] f32 -> bf16 swizzled
    #pragma unroll
    for (int i = 0; i < 16; ++i) {
        int fi = i * 256 + t;
        int r = fi >> 6, c4 = fi & 63;
        float4 v = *reinterpret_cast<const float4*>(&hin[(size_t)(grow0 + r) * Fin + c4 * 4]);
        uint2 pk = make_uint2(cvt_pk_bf16(v.x, v.y), cvt_pk_bf16(v.z, v.w));
        *reinterpret_cast<uint2*>(reinterpret_cast<char*>(Asm) + r * 512 +
            (((c4 >> 1) ^ ((r >> 1) & 7)) << 4) + ((c4 & 1) << 3)) = pk;
    }
    // stage B: W[k][col0..+64] -> Bsm[col][k] bf16 swizzled (transpose via k-pairs)
    #pragma unroll
    for (int i = 0; i < 32; ++i) {
        int p = i * 256 + t;          // pair index: c = p&63, k = (p>>6)*2
        int c = p & 63, k = (p >> 6) << 1;
        float w0 = W[(size_t)k * Cc + col0 + c];
        float w1 = W[(size_t)(k + 1) * Cc + col0 + c];
        unsigned pk = cvt_pk_bf16(w0, w1);
        *reinterpret_cast<unsigned*>(reinterpret_cast<char*>(Bsm) + c * 512 +
            (((k >> 3) ^ ((c >> 1) & 7)) << 4) + ((k & 7) << 1)) = pk;
    }
    __syncthreads();

    const int w = t >> 6, l = t & 63;
    const int lr = l & 15, lg = l >> 4;
    const int ar = w * 16 + lr;       // A-fragment row (within tile)
    f32x4 acc[4] = {{0.f,0.f,0.f,0.f},{0.f,0.f,0.f,0.f},{0.f,0.f,0.f,0.f},{0.f,0.f,0.f,0.f}};

    #pragma unroll
    for (int ks = 0; ks < 8; ++ks) {
        bf16x8 af = *reinterpret_cast<const bf16x8*>(reinterpret_cast<char*>(Asm) +
            ar * 512 + ((((ks << 2) + lg) ^ ((ar >> 1) & 7)) << 4));
        #pragma unroll
        for (int n = 0; n < 4; ++n) {
            int c = n * 16 + lr;
            bf16x8 bf = *reinterpret_cast<const bf16x8*>(reinterpret_cast<char*>(Bsm) +
                c * 512 + ((((ks << 2) + lg) ^ ((c >> 1) & 7)) << 4));
            acc[n] = __builtin_amdgcn_mfma_f32_16x16x32_bf16(af, bf, acc[n], 0, 0, 0);
        }
    }

    // epilogue 1: sC fragment stores (bh = b*8 + hp*2 + (n>>1), fh = n&1)
    const int jt16 = (row0m >> 4) + w;
    #pragma unroll
    for (int n = 0; n < 4; ++n) {
        int bh = b * 8 + hp * 2 + (n >> 1);
        uint2 pk = make_uint2(cvt_pk_bf16(acc[n][0], acc[n][1]),
                              cvt_pk_bf16(acc[n][2], acc[n][3]));
        *reinterpret_cast<uint2*>(reinterpret_cast<char*>(sC) +
            ((((size_t)bh * 64 + jt16) * 2 + (n & 1)) * 64 + l) * 8) = pk;
    }

    // epilogue 2: ei/ej dots over cols via shfl reduce (C rows = lg*4+reg)
    float aL0 = av[lr], aL1 = av[16 + lr], aR0 = av[32 + lr], aR1 = av[48 + lr];
    #pragma unroll
    for (int hh = 0; hh < 2; ++hh) {
        float pi[4], pj[4];
        #pragma unroll
        for (int reg = 0; reg < 4; ++reg) {
            pi[reg] = acc[hh * 2][reg] * aL0 + acc[hh * 2 + 1][reg] * aL1;
            pj[reg] = acc[hh * 2][reg] * aR0 + acc[hh * 2 + 1][reg] * aR1;
        }
        #pragma unroll
        for (int m = 1; m < 16; m <<= 1) {
            #pragma unroll
            for (int reg = 0; reg < 4; ++reg) {
                pi[reg] += __shfl_xor(pi[reg], m);
                pj[reg] += __shfl_xor(pj[reg], m);
            }
        }
        if (lr == 0) {
            int bh = b * 8 + hp * 2 + hh;
            #pragma unroll
            for (int reg = 0; reg < 4; ++reg) {
                int row = row0m + w * 16 + lg * 4 + reg;
                eiT[bh * Nn + row] = pi[reg] * L2E;
                ejT[bh * Nn + row] = pj[reg] * L2E;
            }
        }
    }
}

// ---------------- K2: column sums Z[b,j,h] + transposed adjacency bitmask ----------------
// grid (16 ic, 16 jt, 4 b) = 1024 blocks; wave handles 16 rows, 4 adj loads in flight.
__global__ __launch_bounds__(256) void k_colsum(const float* __restrict__ eiT,
                                                const float* __restrict__ ejT,
                                                const int* __restrict__ adj,
                                                float* __restrict__ Zp,
                                                unsigned long long* __restrict__ adjBT) {
    const int ic = blockIdx.x;
    const int jt = blockIdx.y;
    const int b  = blockIdx.z;
    const int i0 = ic * 64;
    const int j0 = jt * 64;
    const int t = threadIdx.x;
    const int jj = t & 63;
    const int g = t >> 6;
    __shared__ float eis[64 * Hh];         // [i][h]
    __shared__ float red[4 * 64 * Hh];
    for (int v = t; v < 64 * Hh; v += 256) {
        int h = v >> 6, i = v & 63;
        eis[i * Hh + h] = eiT[((size_t)b * Hh + h) * Nn + i0 + i];
    }
    float ejr[Hh];
    #pragma unroll
    for (int hh = 0; hh < Hh; ++hh)
        ejr[hh] = ejT[((size_t)b * Hh + hh) * Nn + j0 + jj];
    __syncthreads();
    float z[Hh] = {};
    const int* ap = &adj[((size_t)b * Nn + i0 + g * 16) * Nn + j0 + jj];
    #pragma unroll 4
    for (int ii = 0; ii < 16; ++ii) {
        int a = ap[(size_t)ii * Nn];
        unsigned long long bal = __ballot(a != 0);
        if (jj == 0)
            adjBT[((size_t)b * 16 + jt) * Nn + (i0 + g * 16 + ii)] = bal;
        float mf = (float)(a != 0);
        const float* ep = &eis[(g * 16 + ii) * Hh];
        #pragma unroll
        for (int hh = 0; hh < Hh; ++hh) {
            float x = ep[hh] + ejr[hh];
            x = fmaxf(x, Alpha * x);
            z[hh] = fmaf(mf, exp2f(x), z[hh]);
        }
    }
    #pragma unroll
    for (int hh = 0; hh < Hh; ++hh)
        red[(g * 64 + jj) * Hh + hh] = z[hh];
    __syncthreads();
    for (int v = t; v < 64 * Hh; v += 256) {
        float sum = red[v] + red[512 + v] + red[1024 + v] + red[1536 + v];
        Zp[(size_t)ic * (Bb * Nn * Hh) + ((size_t)b * Nn + j0) * Hh + v] = sum;
    }
}

// ---------------- K3: ezrT[bh][j] = {ej_scaled, 1/Z} ----------------
__global__ void k_ezrT(const float* __restrict__ Zp, const float* __restrict__ ejT,
                       float2* __restrict__ ezrT) {
    const int tid = blockIdx.x * 256 + threadIdx.x;   // [bh][n], 32768
    const int n = tid & 1023;
    const int bh = tid >> 10;
    const int b = bh >> 3, h = bh & 7;
    const int src = (b * Nn + n) * Hh + h;
    constexpr int S = Bb * Nn * Hh;
    float sum = 0.f;
    #pragma unroll
    for (int c = 0; c < NCHUNK; ++c) sum += Zp[(size_t)c * S + src];
    ezrT[tid] = make_float2(ejT[tid], 1.0f / sum);
}

// ---------------- K4: MFMA aggregation: out = (E.rz) @ s_bf16 + bias ----------------
// B-operand from sC fragment layout: two u64 loads per frag (regs 0..3 / 4..7).
__global__ __launch_bounds__(256) void k_agg(const unsigned short* __restrict__ sC,
                                             const float* __restrict__ eiT,
                                             const float2* __restrict__ ezrT,
                                             const unsigned long long* __restrict__ adjBT,
                                             const float* __restrict__ bias,
                                             float* __restrict__ out) {
    const int bid = blockIdx.x;
    const int xcd = bid & 7, g = bid >> 3;
    const int bh = xcd * 4 + (g & 3);
    const int it = g >> 2;
    const int b = bh >> 3, h = bh & 7;
    const int t = threadIdx.x, w = t >> 6, l = t & 63;
    const int lg = l >> 4;
    const int row = it * 64 + w * 16 + (l & 15);
    const float ei_r = eiT[bh * Nn + row];

    const float4* ez4 = reinterpret_cast<const float4*>(ezrT + (size_t)bh * Nn);
    const unsigned long long* scp =
        reinterpret_cast<const unsigned long long*>(sC) + (size_t)bh * 8192;
    const int lpos = ((l >> 4) & 1) * 32 + (l & 15);

    f32x4 acc0 = {0.f, 0.f, 0.f, 0.f}, acc1 = {0.f, 0.f, 0.f, 0.f};

    for (int jk = 0; jk < 32; ++jk) {
        const int j8 = jk * 32 + lg * 8;
        float4 za = ez4[(j8 >> 1) + 0];
        float4 zb = ez4[(j8 >> 1) + 1];
        float4 zc = ez4[(j8 >> 1) + 2];
        float4 zd = ez4[(j8 >> 1) + 3];
        unsigned long long m64 = adjBT[((size_t)b * 16 + (jk >> 1)) * Nn + row];
        unsigned mb = (unsigned)(m64 >> ((jk & 1) * 32 + lg * 8)) & 0xFFu;

        float wv[8];
        {
            float ejv[8] = {za.x, za.z, zb.x, zb.z, zc.x, zc.z, zd.x, zd.z};
            float rzv[8] = {za.y, za.w, zb.y, zb.w, zc.y, zc.w, zd.y, zd.w};
            #pragma unroll
            for (int e = 0; e < 8; ++e) {
                float x = ei_r + ejv[e];
                x = fmaxf(x, Alpha * x);
                float ww = exp2f(x) * rzv[e];
                wv[e] = ((mb >> e) & 1u) ? ww : 0.0f;
            }
        }
        union { bf16x8 v; unsigned u[4]; } A;
        A.u[0] = cvt_pk_bf16(wv[0], wv[1]);
        A.u[1] = cvt_pk_bf16(wv[2], wv[3]);
        A.u[2] = cvt_pk_bf16(wv[4], wv[5]);
        A.u[3] = cvt_pk_bf16(wv[6], wv[7]);

        const int j16 = jk * 2 + (l >> 5);
        union { bf16x8 v; unsigned long long q[2]; } B0, B1;
        const unsigned long long* p0 = scp + ((size_t)j16 * 2 + 0) * 64 + lpos;
        const unsigned long long* p1 = scp + ((size_t)j16 * 2 + 1) * 64 + lpos;
        B0.q[0] = p0[0];  B0.q[1] = p0[16];
        B1.q[0] = p1[0];  B1.q[1] = p1[16];

        acc0 = __builtin_amdgcn_mfma_f32_16x16x32_bf16(A.v, B0.v, acc0, 0, 0, 0);
        acc1 = __builtin_amdgcn_mfma_f32_16x16x32_bf16(A.v, B1.v, acc1, 0, 0, 0);
    }

    const int col = l & 15;
    const float bv0 = bias[h * Hid + col];
    const float bv1 = bias[h * Hid + 16 + col];
    const int r0 = it * 64 + w * 16 + lg * 4;
    #pragma unroll
    for (int reg = 0; reg < 4; ++reg) {
        float* op = &out[((size_t)b * Nn + r0 + reg) * Cc + h * Hid];
        op[col]      = acc0[reg] + bv0;
        op[16 + col] = acc1[reg] + bv1;
    }
}

extern "C" void kernel_launch(void* const* d_in, const int* in_sizes, int n_in,
                              void* d_out, int out_size, void* d_ws, size_t ws_size,
                              hipStream_t stream) {
    const float* hin  = (const float*)d_in[0];
    const int*   adj  = (const int*)d_in[1];
    const float* W    = (const float*)d_in[2];
    const float* a    = (const float*)d_in[3];
    const float* bias = (const float*)d_in[4];
    float* out = (float*)d_out;
    float* ws  = (float*)d_ws;

    float*  eiT  = ws;                                    // 32,768
    float*  ejT  = ws + 32768;                            // 32,768
    float*  Zp   = ws + 65536;                            // 16 x 32,768
    float2* ezrT = (float2*)(ws + 589824);                // 32,768 float2
    unsigned long long* adjBT = (unsigned long long*)(ws + 655360);  // 65,536 u64
    unsigned short* sC = (unsigned short*)(ws + 786432);  // 1,048,576 bf16

    k_gemm  <<<dim3(4, 64),                 256, 0, stream>>>(hin, W, a, eiT, ejT, sC);
    k_colsum<<<dim3(16, 16, 4),             256, 0, stream>>>(eiT, ejT, adj, Zp, adjBT);
    k_ezrT  <<<dim3((Bb * Nn * Hh) / 256),  256, 0, stream>>>(Zp, ejT, ezrT);
    k_agg   <<<dim3(512),                   256, 0, stream>>>(sC, eiT, ezrT, adjBT, bias, out);
}